// Round 4
// baseline (605.310 us; speedup 1.0000x reference)
//
#include <hip/hip_runtime.h>
#include <math.h>

#define NROW 16384   // B*N rows
#define NCOL 4096
#define CDIM 256
#define DKDIM 64
#define SCALE 0.125f // DK^-0.5

typedef float v4f __attribute__((ext_vector_type(4)));  // for nontemporal stores

// ---------------- Kernel 1: fused Q/K projection ----------------
// Output layout (both Q and K): T4[(b*16 + dg)*4096 + n] = proj[n][4*dg .. 4*dg+3]
// (b = batch, dg = d-group of 4, n = row within batch). This makes both the
// per-row register loads (lane-consecutive) and the per-col scalar loads
// (col-consecutive) in kernel 2 contiguous.
__global__ __launch_bounds__(512, 2) void qk_proj(
    const float* __restrict__ x, const float* __restrict__ Wq,
    const float* __restrict__ Wk, float* __restrict__ Qt,
    float* __restrict__ Kt) {
  __shared__ float4 xs4[64][65];  // row stride 65 f4-units -> bank-group spread
  const int t = threadIdx.x;
  const int rb = blockIdx.x;      // 256 blocks of 64 rows
  {
    const float4* xg = (const float4*)(x + (size_t)rb * 64 * CDIM);
    #pragma unroll
    for (int i = 0; i < 8; ++i) {
      int idx = i * 512 + t;      // 0..4095
      xs4[idx >> 6][idx & 63] = xg[idx];
    }
  }
  __syncthreads();

  const int lane = t & 63;
  const int wu = __builtin_amdgcn_readfirstlane(t >> 6);  // wave id, uniform
  const int proj = wu >> 2;
  const int chunk = wu & 3;       // d-chunk: d = chunk*16 .. +15
  const float* __restrict__ Wp = proj ? Wk : Wq;

  float acc[16];
  #pragma unroll
  for (int j = 0; j < 16; ++j) acc[j] = 0.f;

  #pragma unroll 4
  for (int cs = 0; cs < 64; ++cs) {        // 4 c's per step
    float4 xv = xs4[lane][cs];
    const float xc[4] = {xv.x, xv.y, xv.z, xv.w};
    #pragma unroll
    for (int i = 0; i < 4; ++i) {
      // uniform address -> scalar loads of W[(4cs+i)][chunk*16 .. +15]
      const float4* __restrict__ w4 =
          (const float4*)(Wp + (size_t)(cs * 4 + i) * DKDIM + chunk * 16);
      float4 wa = w4[0], wb = w4[1], wc = w4[2], wd = w4[3];
      float xi = xc[i];
      acc[0]  = fmaf(xi, wa.x, acc[0]);  acc[1]  = fmaf(xi, wa.y, acc[1]);
      acc[2]  = fmaf(xi, wa.z, acc[2]);  acc[3]  = fmaf(xi, wa.w, acc[3]);
      acc[4]  = fmaf(xi, wb.x, acc[4]);  acc[5]  = fmaf(xi, wb.y, acc[5]);
      acc[6]  = fmaf(xi, wb.z, acc[6]);  acc[7]  = fmaf(xi, wb.w, acc[7]);
      acc[8]  = fmaf(xi, wc.x, acc[8]);  acc[9]  = fmaf(xi, wc.y, acc[9]);
      acc[10] = fmaf(xi, wc.z, acc[10]); acc[11] = fmaf(xi, wc.w, acc[11]);
      acc[12] = fmaf(xi, wd.x, acc[12]); acc[13] = fmaf(xi, wd.y, acc[13]);
      acc[14] = fmaf(xi, wd.z, acc[14]); acc[15] = fmaf(xi, wd.w, acc[15]);
    }
  }

  const int gr = rb * 64 + lane;  // global row
  const int b = gr >> 12;
  const int n = gr & 4095;
  float4* __restrict__ Out4 = (float4*)(proj ? Kt : Qt);
  #pragma unroll
  for (int i = 0; i < 4; ++i) {
    int dg = chunk * 4 + i;
    float4 o = {acc[4 * i], acc[4 * i + 1], acc[4 * i + 2], acc[4 * i + 3]};
    Out4[(size_t)(b * 16 + dg) * 4096 + n] = o;  // lane-consecutive: coalesced
  }
}

// ---------------- Kernel 2: fused S = Q K^T + per-row top-8 ----------------
// Grid (256 rowblocks, 4 col-chunks of 1024). Block 256 thr = 4 waves.
// lane = row: Q row pinned in 64 VGPRs (asm pin prevents demotion); wave w
// owns a 256-col stripe; K frags are wave-uniform -> scalar loads, kept to
// 2 s_load_dwordx16 per g-step (8-col tile) so SGPRs never spill.
// Also zero-fills its 64x1024 output region (overlaps the HBM write floor).
__global__ __launch_bounds__(256, 4) void s_topk(
    const float* __restrict__ Qt, const float* __restrict__ Kt,
    float* __restrict__ out, float* __restrict__ wsv, int* __restrict__ wsi) {
  __shared__ float cv[64][33];
  __shared__ int   ci[64][33];
  const int t = threadIdx.x;
  const int rb = blockIdx.x;       // 0..255
  const int chunk = blockIdx.y;    // 0..3
  const int lane = t & 63;
  const int wu = __builtin_amdgcn_readfirstlane(t >> 6);  // wave id
  const int b = rb >> 6;
  const int nb = (rb & 63) * 64;   // row base within batch

  // 1) zero-fill my 64 x 1024 output region (fire-and-forget, nontemporal)
  {
    v4f z = {0.f, 0.f, 0.f, 0.f};
    v4f* o4 = (v4f*)out + (size_t)rb * 64 * 1024 + chunk * 256;
    #pragma unroll 8
    for (int i = 0; i < 64; ++i) {
      int g = i * 256 + t;         // 0..16383: 64 rows x 256 f4
      __builtin_nontemporal_store(z, &o4[(size_t)(g >> 8) * 1024 + (g & 255)]);
    }
  }

  // 2) my Q row into 64 VGPRs, pinned so the allocator can't demote it
  const float4* __restrict__ Qt4 = (const float4*)Qt;
  float q[64];
  #pragma unroll
  for (int g = 0; g < 16; ++g) {
    float4 v = Qt4[(size_t)(b * 16 + g) * 4096 + nb + lane];
    q[4 * g] = v.x; q[4 * g + 1] = v.y; q[4 * g + 2] = v.z; q[4 * g + 3] = v.w;
  }
  #pragma unroll
  for (int i = 0; i < 64; ++i) asm volatile("" : "+v"(q[i]));

  // 3) per-lane top-8 state (cached min + its slot)
  float tv[8]; int ti[8]; float tmin = -INFINITY; int tmpos = 0;
  #pragma unroll
  for (int q2 = 0; q2 < 8; ++q2) { tv[q2] = -INFINITY; ti[q2] = 0; }

  const float4* __restrict__ Kt4 = (const float4*)Kt;
  const int stripe = chunk * 1024 + wu * 256;  // my wave's col stripe base

  #pragma unroll 1
  for (int cg = 0; cg < 32; ++cg) {  // 32 col-groups of 8 cols
    const int cb = stripe + cg * 8;
    float acc[8];
    #pragma unroll
    for (int j = 0; j < 8; ++j) acc[j] = 0.f;
    #pragma unroll
    for (int g = 0; g < 16; ++g) {
      // uniform address -> 2x s_load_dwordx16 (128B contiguous, shared by wave)
      const float4* __restrict__ kg = Kt4 + (size_t)(b * 16 + g) * 4096 + cb;
      #pragma unroll
      for (int j = 0; j < 8; ++j) {
        float4 kf = kg[j];
        acc[j] = fmaf(q[4 * g],     kf.x, acc[j]);
        acc[j] = fmaf(q[4 * g + 1], kf.y, acc[j]);
        acc[j] = fmaf(q[4 * g + 2], kf.z, acc[j]);
        acc[j] = fmaf(q[4 * g + 3], kf.w, acc[j]);
      }
    }
    // top-8 update (skip whole group if its max can't beat current min)
    float tmax = acc[0];
    #pragma unroll
    for (int j = 1; j < 8; ++j) tmax = fmaxf(tmax, acc[j]);
    if (tmax > tmin) {
      #pragma unroll
      for (int j = 0; j < 8; ++j) {
        float v = acc[j];
        if (v > tmin) {
          int col = cb + j;
          #pragma unroll
          for (int q2 = 0; q2 < 8; ++q2)
            if (q2 == tmpos) { tv[q2] = v; ti[q2] = col; }
          tmin = tv[0]; tmpos = 0;
          #pragma unroll
          for (int q2 = 1; q2 < 8; ++q2)
            if (tv[q2] < tmin) { tmin = tv[q2]; tmpos = q2; }
        }
      }
    }
  }

  // 4) block merge: 4 waves x 8 candidates -> chunk-local top-8 per row
  #pragma unroll
  for (int q2 = 0; q2 < 8; ++q2) {
    cv[lane][wu * 8 + q2] = tv[q2];
    ci[lane][wu * 8 + q2] = ti[q2];
  }
  __syncthreads();
  if (t < 64) {
    float rv[8]; int rid[8];
    #pragma unroll
    for (int q2 = 0; q2 < 8; ++q2) { rv[q2] = cv[t][q2]; rid[q2] = ci[t][q2]; }
    float m = rv[0]; int mp = 0;
    #pragma unroll
    for (int q2 = 1; q2 < 8; ++q2) if (rv[q2] < m) { m = rv[q2]; mp = q2; }
    #pragma unroll
    for (int c = 8; c < 32; ++c) {
      float v = cv[t][c];
      if (v > m) {
        int col = ci[t][c];
        #pragma unroll
        for (int q2 = 0; q2 < 8; ++q2) if (q2 == mp) { rv[q2] = v; rid[q2] = col; }
        m = rv[0]; mp = 0;
        #pragma unroll
        for (int q2 = 1; q2 < 8; ++q2) if (rv[q2] < m) { m = rv[q2]; mp = q2; }
      }
    }
    size_t gr = (size_t)rb * 64 + t;
    #pragma unroll
    for (int q2 = 0; q2 < 8; ++q2) {
      wsv[gr * 32 + chunk * 8 + q2] = rv[q2];
      wsi[gr * 32 + chunk * 8 + q2] = rid[q2];
    }
  }
}

// ---------------- Kernel 3: merge 4 chunks, softmax, scatter ----------------
__global__ __launch_bounds__(256) void merge_scatter(
    const float* __restrict__ wsv, const int* __restrict__ wsi,
    float* __restrict__ out) {
  int row = blockIdx.x * 256 + threadIdx.x;  // 0..16383
  float v[32]; int id[32];
  const float4* v4 = (const float4*)(wsv + (size_t)row * 32);
  const int4*   i4 = (const int4*)(wsi + (size_t)row * 32);
  #pragma unroll
  for (int i = 0; i < 8; ++i) {
    float4 a = v4[i]; v[4*i] = a.x; v[4*i+1] = a.y; v[4*i+2] = a.z; v[4*i+3] = a.w;
    int4   c = i4[i]; id[4*i] = c.x; id[4*i+1] = c.y; id[4*i+2] = c.z; id[4*i+3] = c.w;
  }
  float rv[8]; int rid[8];
  #pragma unroll
  for (int q = 0; q < 8; ++q) { rv[q] = v[q]; rid[q] = id[q]; }
  float m = rv[0]; int mp = 0;
  #pragma unroll
  for (int q = 1; q < 8; ++q) if (rv[q] < m) { m = rv[q]; mp = q; }
  #pragma unroll
  for (int c = 8; c < 32; ++c) {
    if (v[c] > m) {
      #pragma unroll
      for (int q = 0; q < 8; ++q) if (q == mp) { rv[q] = v[c]; rid[q] = id[c]; }
      m = rv[0]; mp = 0;
      #pragma unroll
      for (int q = 1; q < 8; ++q) if (rv[q] < m) { m = rv[q]; mp = q; }
    }
  }
  float vmax = rv[0];
  #pragma unroll
  for (int q = 1; q < 8; ++q) vmax = fmaxf(vmax, rv[q]);
  float e[8], s = 0.f;
  #pragma unroll
  for (int q = 0; q < 8; ++q) { e[q] = __expf((rv[q] - vmax) * SCALE); s += e[q]; }
  float inv = 1.f / s;
  float* orow = out + (size_t)row * NCOL;
  #pragma unroll
  for (int q = 0; q < 8; ++q) orow[rid[q]] = e[q] * inv;
}

extern "C" void kernel_launch(void* const* d_in, const int* in_sizes, int n_in,
                              void* d_out, int out_size, void* d_ws, size_t ws_size,
                              hipStream_t stream) {
  const float* x  = (const float*)d_in[0];
  const float* Wq = (const float*)d_in[1];
  const float* Wk = (const float*)d_in[2];
  float* out = (float*)d_out;

  char* ws = (char*)d_ws;
  float* Qt  = (float*)ws;                                   // 4 MB
  float* Kt  = (float*)(ws + (size_t)NROW * DKDIM * 4);      // 4 MB
  float* wsv = (float*)(ws + 2 * (size_t)NROW * DKDIM * 4);  // 2 MB
  int*   wsi = (int*)  (ws + 2 * (size_t)NROW * DKDIM * 4 + (size_t)NROW * 32 * 4); // 2 MB

  qk_proj<<<dim3(NROW / 64), 512, 0, stream>>>(x, Wq, Wk, Qt, Kt);
  s_topk<<<dim3(NROW / 64, 4), 256, 0, stream>>>(Qt, Kt, out, wsv, wsi);
  merge_scatter<<<NROW / 256, 256, 0, stream>>>(wsv, wsi, out);
}

// Round 5
// 576.635 us; speedup vs baseline: 1.0497x; 1.0497x over previous
//
#include <hip/hip_runtime.h>
#include <math.h>

#define NROW 16384   // B*N rows
#define NCOL 4096
#define CDIM 256
#define DKDIM 64
#define SCALE 0.125f // DK^-0.5

typedef float v4f __attribute__((ext_vector_type(4)));  // for nontemporal stores

// ---------------- Kernel 1: fused Q/K projection ----------------
// Output layout (both Q and K): T4[(b*16 + dg)*4096 + n] = proj[n][4*dg .. 4*dg+3]
__global__ __launch_bounds__(512, 2) void qk_proj(
    const float* __restrict__ x, const float* __restrict__ Wq,
    const float* __restrict__ Wk, float* __restrict__ Qt,
    float* __restrict__ Kt) {
  __shared__ float4 xs4[64][65];  // row stride 65 f4-units -> bank-group spread
  const int t = threadIdx.x;
  const int rb = blockIdx.x;      // 256 blocks of 64 rows
  {
    const float4* xg = (const float4*)(x + (size_t)rb * 64 * CDIM);
    #pragma unroll
    for (int i = 0; i < 8; ++i) {
      int idx = i * 512 + t;      // 0..4095
      xs4[idx >> 6][idx & 63] = xg[idx];
    }
  }
  __syncthreads();

  const int lane = t & 63;
  const int wu = __builtin_amdgcn_readfirstlane(t >> 6);  // wave id, uniform
  const int proj = wu >> 2;
  const int chunk = wu & 3;       // d-chunk: d = chunk*16 .. +15
  const float* __restrict__ Wp = proj ? Wk : Wq;

  float acc[16];
  #pragma unroll
  for (int j = 0; j < 16; ++j) acc[j] = 0.f;

  #pragma unroll 4
  for (int cs = 0; cs < 64; ++cs) {        // 4 c's per step
    float4 xv = xs4[lane][cs];
    const float xc[4] = {xv.x, xv.y, xv.z, xv.w};
    #pragma unroll
    for (int i = 0; i < 4; ++i) {
      const float4* __restrict__ w4 =
          (const float4*)(Wp + (size_t)(cs * 4 + i) * DKDIM + chunk * 16);
      float4 wa = w4[0], wb = w4[1], wc = w4[2], wd = w4[3];
      float xi = xc[i];
      acc[0]  = fmaf(xi, wa.x, acc[0]);  acc[1]  = fmaf(xi, wa.y, acc[1]);
      acc[2]  = fmaf(xi, wa.z, acc[2]);  acc[3]  = fmaf(xi, wa.w, acc[3]);
      acc[4]  = fmaf(xi, wb.x, acc[4]);  acc[5]  = fmaf(xi, wb.y, acc[5]);
      acc[6]  = fmaf(xi, wb.z, acc[6]);  acc[7]  = fmaf(xi, wb.w, acc[7]);
      acc[8]  = fmaf(xi, wc.x, acc[8]);  acc[9]  = fmaf(xi, wc.y, acc[9]);
      acc[10] = fmaf(xi, wc.z, acc[10]); acc[11] = fmaf(xi, wc.w, acc[11]);
      acc[12] = fmaf(xi, wd.x, acc[12]); acc[13] = fmaf(xi, wd.y, acc[13]);
      acc[14] = fmaf(xi, wd.z, acc[14]); acc[15] = fmaf(xi, wd.w, acc[15]);
    }
  }

  const int gr = rb * 64 + lane;  // global row
  const int b = gr >> 12;
  const int n = gr & 4095;
  float4* __restrict__ Out4 = (float4*)(proj ? Kt : Qt);
  #pragma unroll
  for (int i = 0; i < 4; ++i) {
    int dg = chunk * 4 + i;
    float4 o = {acc[4 * i], acc[4 * i + 1], acc[4 * i + 2], acc[4 * i + 3]};
    Out4[(size_t)(b * 16 + dg) * 4096 + n] = o;  // lane-consecutive: coalesced
  }
}

// ---------------- Kernel 2: fused S = Q K^T + per-row top-8 ----------------
// Grid (256 rowblocks, 4 col-chunks of 1024). Block 256 thr = 4 waves.
// lane = row; Q rows staged in LDS (1 ds_read_b128/g-step, no register
// pressure); wave w owns a 256-col stripe; K frags wave-uniform -> scalar
// loads, unroll capped at 2 g-steps so live K SGPRs stay < 102 (no spills).
// Top-8 kept per lane; per 8-col group: argmax + up-to-2 guarded inserts
// behind wave-uniform __any branches + rare full fallback.
__global__ __launch_bounds__(256, 8) void s_topk(
    const float* __restrict__ Qt, const float* __restrict__ Kt,
    float* __restrict__ out, float* __restrict__ wsv, int* __restrict__ wsi) {
  __shared__ float smem[4224];            // 16.9 KB: q-stage / merge union
  float4* qs = (float4*)smem;             // [g*64 + row], 1024 float4 = 16 KB
  float (*cv)[33] = (float(*)[33])smem;   // merge view (aliases qs)
  int   (*ci)[33] = (int(*)[33])(smem + 64 * 33);

  const int t = threadIdx.x;
  const int rb = blockIdx.x;       // 0..255
  const int chunk = blockIdx.y;    // 0..3
  const int lane = t & 63;
  const int wu = __builtin_amdgcn_readfirstlane(t >> 6);  // wave id
  const int b = rb >> 6;
  const int nb = (rb & 63) * 64;   // row base within batch

  // 1) stage Q rows into LDS (coalesced global, stride-16B LDS writes)
  const float4* __restrict__ Qt4 = (const float4*)Qt;
  #pragma unroll
  for (int i = 0; i < 4; ++i) {
    int idx = i * 256 + t;         // 0..1023
    int g = idx >> 6, row = idx & 63;
    qs[g * 64 + row] = Qt4[(size_t)(b * 16 + g) * 4096 + nb + row];
  }
  __syncthreads();

  // 2) zero-fill my 64x1024 output region AFTER the barrier (fire-and-forget,
  //    nontemporal; drains in the background during the cg loop)
  {
    v4f z = {0.f, 0.f, 0.f, 0.f};
    v4f* o4 = (v4f*)out + (size_t)rb * 64 * 1024 + chunk * 256;
    #pragma unroll 8
    for (int i = 0; i < 64; ++i) {
      int g = i * 256 + t;         // 0..16383: 64 rows x 256 f4
      __builtin_nontemporal_store(z, &o4[(size_t)(g >> 8) * 1024 + (g & 255)]);
    }
  }

  const float4* __restrict__ Kt4 = (const float4*)Kt;
  const int stripe = chunk * 1024 + wu * 256;  // my wave's col stripe base

  float tv[8]; int ti[8]; float tmin; int tmpos;

  auto compute8 = [&](int cb, float* acc) {
    #pragma unroll
    for (int j = 0; j < 8; ++j) acc[j] = 0.f;
    #pragma unroll 2
    for (int g = 0; g < 16; ++g) {
      float4 qf = qs[g * 64 + lane];                      // ds_read_b128
      const float4* __restrict__ kg =
          Kt4 + (size_t)(b * 16 + g) * 4096 + cb;         // uniform -> s_load
      #pragma unroll
      for (int j = 0; j < 8; ++j) {
        float4 kf = kg[j];
        acc[j] = fmaf(qf.x, kf.x, acc[j]);
        acc[j] = fmaf(qf.y, kf.y, acc[j]);
        acc[j] = fmaf(qf.z, kf.z, acc[j]);
        acc[j] = fmaf(qf.w, kf.w, acc[j]);
      }
    }
  };

  // 3) seed top-8 with the first 8-col group (no compares needed)
  {
    float acc[8];
    compute8(stripe, acc);
    #pragma unroll
    for (int j = 0; j < 8; ++j) { tv[j] = acc[j]; ti[j] = stripe + j; }
    tmin = tv[0]; tmpos = 0;
    #pragma unroll
    for (int q2 = 1; q2 < 8; ++q2)
      if (tv[q2] < tmin) { tmin = tv[q2]; tmpos = q2; }
  }

  // 4) remaining 31 groups
  #pragma unroll 1
  for (int cg = 1; cg < 32; ++cg) {
    const int cb = stripe + cg * 8;
    float acc[8];
    compute8(cb, acc);

    float bv = acc[0]; int bj = 0;
    #pragma unroll
    for (int j = 1; j < 8; ++j)
      if (acc[j] > bv) { bv = acc[j]; bj = j; }

    #pragma unroll
    for (int pass = 0; pass < 2; ++pass) {
      if (__any(bv > tmin)) {            // wave-uniform branch
        if (bv > tmin) {                 // per-lane insert
          int col = cb + bj;
          #pragma unroll
          for (int q2 = 0; q2 < 8; ++q2)
            if (q2 == tmpos) { tv[q2] = bv; ti[q2] = col; }
          tmin = tv[0]; tmpos = 0;
          #pragma unroll
          for (int q2 = 1; q2 < 8; ++q2)
            if (tv[q2] < tmin) { tmin = tv[q2]; tmpos = q2; }
          #pragma unroll
          for (int j = 0; j < 8; ++j)
            if (j == bj) acc[j] = -INFINITY;
        }
        bv = acc[0]; bj = 0;
        #pragma unroll
        for (int j = 1; j < 8; ++j)
          if (acc[j] > bv) { bv = acc[j]; bj = j; }
      }
    }
    // rare fallback: some lane had >=3 qualifiers in this group
    if (__any(bv > tmin)) {
      #pragma unroll
      for (int j = 0; j < 8; ++j) {
        float v = acc[j];
        if (v > tmin) {
          int col = cb + j;
          #pragma unroll
          for (int q2 = 0; q2 < 8; ++q2)
            if (q2 == tmpos) { tv[q2] = v; ti[q2] = col; }
          tmin = tv[0]; tmpos = 0;
          #pragma unroll
          for (int q2 = 1; q2 < 8; ++q2)
            if (tv[q2] < tmin) { tmin = tv[q2]; tmpos = q2; }
        }
      }
    }
  }

  // 5) block merge: 4 waves x 8 candidates -> chunk-local top-8 per row
  __syncthreads();                 // all q reads done before aliasing cv/ci
  #pragma unroll
  for (int q2 = 0; q2 < 8; ++q2) {
    cv[lane][wu * 8 + q2] = tv[q2];
    ci[lane][wu * 8 + q2] = ti[q2];
  }
  __syncthreads();
  if (t < 64) {
    float rv[8]; int rid[8];
    #pragma unroll
    for (int q2 = 0; q2 < 8; ++q2) { rv[q2] = cv[t][q2]; rid[q2] = ci[t][q2]; }
    float m = rv[0]; int mp = 0;
    #pragma unroll
    for (int q2 = 1; q2 < 8; ++q2) if (rv[q2] < m) { m = rv[q2]; mp = q2; }
    #pragma unroll
    for (int c = 8; c < 32; ++c) {
      float v = cv[t][c];
      if (v > m) {
        int col = ci[t][c];
        #pragma unroll
        for (int q2 = 0; q2 < 8; ++q2) if (q2 == mp) { rv[q2] = v; rid[q2] = col; }
        m = rv[0]; mp = 0;
        #pragma unroll
        for (int q2 = 1; q2 < 8; ++q2) if (rv[q2] < m) { m = rv[q2]; mp = q2; }
      }
    }
    size_t gr = (size_t)rb * 64 + t;
    #pragma unroll
    for (int q2 = 0; q2 < 8; ++q2) {
      wsv[gr * 32 + chunk * 8 + q2] = rv[q2];
      wsi[gr * 32 + chunk * 8 + q2] = rid[q2];
    }
  }
}

// ---------------- Kernel 3: merge 4 chunks, softmax, scatter ----------------
__global__ __launch_bounds__(256) void merge_scatter(
    const float* __restrict__ wsv, const int* __restrict__ wsi,
    float* __restrict__ out) {
  int row = blockIdx.x * 256 + threadIdx.x;  // 0..16383
  float v[32]; int id[32];
  const float4* v4 = (const float4*)(wsv + (size_t)row * 32);
  const int4*   i4 = (const int4*)(wsi + (size_t)row * 32);
  #pragma unroll
  for (int i = 0; i < 8; ++i) {
    float4 a = v4[i]; v[4*i] = a.x; v[4*i+1] = a.y; v[4*i+2] = a.z; v[4*i+3] = a.w;
    int4   c = i4[i]; id[4*i] = c.x; id[4*i+1] = c.y; id[4*i+2] = c.z; id[4*i+3] = c.w;
  }
  float rv[8]; int rid[8];
  #pragma unroll
  for (int q = 0; q < 8; ++q) { rv[q] = v[q]; rid[q] = id[q]; }
  float m = rv[0]; int mp = 0;
  #pragma unroll
  for (int q = 1; q < 8; ++q) if (rv[q] < m) { m = rv[q]; mp = q; }
  #pragma unroll
  for (int c = 8; c < 32; ++c) {
    if (v[c] > m) {
      #pragma unroll
      for (int q = 0; q < 8; ++q) if (q == mp) { rv[q] = v[c]; rid[q] = id[c]; }
      m = rv[0]; mp = 0;
      #pragma unroll
      for (int q = 1; q < 8; ++q) if (rv[q] < m) { m = rv[q]; mp = q; }
    }
  }
  float vmax = rv[0];
  #pragma unroll
  for (int q = 1; q < 8; ++q) vmax = fmaxf(vmax, rv[q]);
  float e[8], s = 0.f;
  #pragma unroll
  for (int q = 0; q < 8; ++q) { e[q] = __expf((rv[q] - vmax) * SCALE); s += e[q]; }
  float inv = 1.f / s;
  float* orow = out + (size_t)row * NCOL;
  #pragma unroll
  for (int q = 0; q < 8; ++q) orow[rid[q]] = e[q] * inv;
}

extern "C" void kernel_launch(void* const* d_in, const int* in_sizes, int n_in,
                              void* d_out, int out_size, void* d_ws, size_t ws_size,
                              hipStream_t stream) {
  const float* x  = (const float*)d_in[0];
  const float* Wq = (const float*)d_in[1];
  const float* Wk = (const float*)d_in[2];
  float* out = (float*)d_out;

  char* ws = (char*)d_ws;
  float* Qt  = (float*)ws;                                   // 4 MB
  float* Kt  = (float*)(ws + (size_t)NROW * DKDIM * 4);      // 4 MB
  float* wsv = (float*)(ws + 2 * (size_t)NROW * DKDIM * 4);  // 2 MB
  int*   wsi = (int*)  (ws + 2 * (size_t)NROW * DKDIM * 4 + (size_t)NROW * 32 * 4); // 2 MB

  qk_proj<<<dim3(NROW / 64), 512, 0, stream>>>(x, Wq, Wk, Qt, Kt);
  s_topk<<<dim3(NROW / 64, 4), 256, 0, stream>>>(Qt, Kt, out, wsv, wsi);
  merge_scatter<<<NROW / 256, 256, 0, stream>>>(wsv, wsi, out);
}

// Round 6
// 537.460 us; speedup vs baseline: 1.1262x; 1.0729x over previous
//
#include <hip/hip_runtime.h>
#include <math.h>

#define NROW 16384   // B*N rows
#define NCOL 4096
#define CDIM 256
#define DKDIM 64
#define SCALE 0.125f // DK^-0.5

typedef float v4f __attribute__((ext_vector_type(4)));  // for nontemporal stores

// ---------------- Kernel 1: fused Q/K projection ----------------
// Output layout (both Q and K): T4[(b*16 + dg)*4096 + n] = proj[n][4*dg .. 4*dg+3]
__global__ __launch_bounds__(512, 2) void qk_proj(
    const float* __restrict__ x, const float* __restrict__ Wq,
    const float* __restrict__ Wk, float* __restrict__ Qt,
    float* __restrict__ Kt) {
  __shared__ float4 xs4[64][65];  // row stride 65 f4-units -> bank-group spread
  const int t = threadIdx.x;
  const int rb = blockIdx.x;      // 256 blocks of 64 rows
  {
    const float4* xg = (const float4*)(x + (size_t)rb * 64 * CDIM);
    #pragma unroll
    for (int i = 0; i < 8; ++i) {
      int idx = i * 512 + t;      // 0..4095
      xs4[idx >> 6][idx & 63] = xg[idx];
    }
  }
  __syncthreads();

  const int lane = t & 63;
  const int wu = __builtin_amdgcn_readfirstlane(t >> 6);  // wave id, uniform
  const int proj = wu >> 2;
  const int chunk = wu & 3;       // d-chunk: d = chunk*16 .. +15
  const float* __restrict__ Wp = proj ? Wk : Wq;

  float acc[16];
  #pragma unroll
  for (int j = 0; j < 16; ++j) acc[j] = 0.f;

  #pragma unroll 4
  for (int cs = 0; cs < 64; ++cs) {        // 4 c's per step
    float4 xv = xs4[lane][cs];
    const float xc[4] = {xv.x, xv.y, xv.z, xv.w};
    #pragma unroll
    for (int i = 0; i < 4; ++i) {
      const float4* __restrict__ w4 =
          (const float4*)(Wp + (size_t)(cs * 4 + i) * DKDIM + chunk * 16);
      float4 wa = w4[0], wb = w4[1], wc = w4[2], wd = w4[3];
      float xi = xc[i];
      acc[0]  = fmaf(xi, wa.x, acc[0]);  acc[1]  = fmaf(xi, wa.y, acc[1]);
      acc[2]  = fmaf(xi, wa.z, acc[2]);  acc[3]  = fmaf(xi, wa.w, acc[3]);
      acc[4]  = fmaf(xi, wb.x, acc[4]);  acc[5]  = fmaf(xi, wb.y, acc[5]);
      acc[6]  = fmaf(xi, wb.z, acc[6]);  acc[7]  = fmaf(xi, wb.w, acc[7]);
      acc[8]  = fmaf(xi, wc.x, acc[8]);  acc[9]  = fmaf(xi, wc.y, acc[9]);
      acc[10] = fmaf(xi, wc.z, acc[10]); acc[11] = fmaf(xi, wc.w, acc[11]);
      acc[12] = fmaf(xi, wd.x, acc[12]); acc[13] = fmaf(xi, wd.y, acc[13]);
      acc[14] = fmaf(xi, wd.z, acc[14]); acc[15] = fmaf(xi, wd.w, acc[15]);
    }
  }

  const int gr = rb * 64 + lane;  // global row
  const int b = gr >> 12;
  const int n = gr & 4095;
  float4* __restrict__ Out4 = (float4*)(proj ? Kt : Qt);
  #pragma unroll
  for (int i = 0; i < 4; ++i) {
    int dg = chunk * 4 + i;
    float4 o = {acc[4 * i], acc[4 * i + 1], acc[4 * i + 2], acc[4 * i + 3]};
    Out4[(size_t)(b * 16 + dg) * 4096 + n] = o;  // lane-consecutive: coalesced
  }
}

// ---------------- Kernel 2: fused S = Q K^T + per-row top-8 ----------------
// Grid: 2048 blocks (8 col-chunks of 512 x 256 rowblocks), flattened 1D with
// an XCD-aware swizzle: blockIdx%8 ~ XCD (dispatch heuristic); all 64 blocks
// sharing one (batch, chunk) K-region land on one XCD -> K+Q footprint
// ~1.5 MB/XCD << 4 MB L2, so the wave-uniform K s_loads hit L2.
// 8 blocks/CU (LDS 16.9 KB) = 32 waves/CU for SMEM-latency hiding.
__global__ __launch_bounds__(256, 8) void s_topk(
    const float* __restrict__ Qt, const float* __restrict__ Kt,
    float* __restrict__ out, float* __restrict__ wsv, int* __restrict__ wsi) {
  __shared__ float smem[4224];            // 16.9 KB: q-stage / merge union
  float4* qs = (float4*)smem;             // [g*64 + row], 1024 float4 = 16 KB
  float (*cv)[33] = (float(*)[33])smem;   // merge view (aliases qs)
  int   (*ci)[33] = (int(*)[33])(smem + 64 * 33);

  const int t = threadIdx.x;
  // XCD swizzle decode: f&7 selects XCD-slot; 4 (b,chunk) combos per slot.
  const int f = blockIdx.x;        // 0..2047
  const int xs = f & 7;
  const int i5 = f >> 3;           // 0..255
  const int combo = xs * 4 + (i5 >> 6);   // 0..31
  const int rbL = i5 & 63;
  const int b = combo >> 3;        // batch
  const int chunk = combo & 7;     // col-chunk of 512
  const int rb = b * 64 + rbL;     // rowblock 0..255
  const int lane = t & 63;
  const int wu = __builtin_amdgcn_readfirstlane(t >> 6);  // wave id
  const int nb = rbL * 64;         // row base within batch

  // 1) stage Q rows into LDS (coalesced global, stride-16B LDS writes)
  const float4* __restrict__ Qt4 = (const float4*)Qt;
  #pragma unroll
  for (int i = 0; i < 4; ++i) {
    int idx = i * 256 + t;         // 0..1023
    int g = idx >> 6, row = idx & 63;
    qs[g * 64 + row] = Qt4[(size_t)(b * 16 + g) * 4096 + nb + row];
  }
  __syncthreads();

  // 2) zero-fill my 64x512 output region (fire-and-forget, nontemporal;
  //    drains in the background during the cg loop)
  {
    v4f z = {0.f, 0.f, 0.f, 0.f};
    v4f* o4 = (v4f*)out + (size_t)rb * 64 * 1024 + chunk * 128;
    #pragma unroll 8
    for (int i = 0; i < 32; ++i) {
      int g = i * 256 + t;         // 0..8191: 64 rows x 128 f4
      __builtin_nontemporal_store(z, &o4[(size_t)(g >> 7) * 1024 + (g & 127)]);
    }
  }

  const float4* __restrict__ Kt4 = (const float4*)Kt;
  const int stripe = chunk * 512 + wu * 128;  // my wave's 128-col stripe

  float tv[8]; int ti[8]; float tmin; int tmpos;

  auto compute8 = [&](int cb, float* acc) {
    #pragma unroll
    for (int j = 0; j < 8; ++j) acc[j] = 0.f;
    #pragma unroll 2
    for (int g = 0; g < 16; ++g) {
      float4 qf = qs[g * 64 + lane];                      // ds_read_b128
      const float4* __restrict__ kg =
          Kt4 + (size_t)(b * 16 + g) * 4096 + cb;         // uniform -> s_load
      #pragma unroll
      for (int j = 0; j < 8; ++j) {
        float4 kf = kg[j];
        acc[j] = fmaf(qf.x, kf.x, acc[j]);
        acc[j] = fmaf(qf.y, kf.y, acc[j]);
        acc[j] = fmaf(qf.z, kf.z, acc[j]);
        acc[j] = fmaf(qf.w, kf.w, acc[j]);
      }
    }
  };

  // 3) seed top-8 with the first 8-col group (no compares needed)
  {
    float acc[8];
    compute8(stripe, acc);
    #pragma unroll
    for (int j = 0; j < 8; ++j) { tv[j] = acc[j]; ti[j] = stripe + j; }
    tmin = tv[0]; tmpos = 0;
    #pragma unroll
    for (int q2 = 1; q2 < 8; ++q2)
      if (tv[q2] < tmin) { tmin = tv[q2]; tmpos = q2; }
  }

  // 4) remaining 15 groups
  #pragma unroll 1
  for (int cg = 1; cg < 16; ++cg) {
    const int cb = stripe + cg * 8;
    float acc[8];
    compute8(cb, acc);

    float bv = acc[0]; int bj = 0;
    #pragma unroll
    for (int j = 1; j < 8; ++j)
      if (acc[j] > bv) { bv = acc[j]; bj = j; }

    #pragma unroll
    for (int pass = 0; pass < 2; ++pass) {
      if (__any(bv > tmin)) {            // wave-uniform branch
        if (bv > tmin) {                 // per-lane insert
          int col = cb + bj;
          #pragma unroll
          for (int q2 = 0; q2 < 8; ++q2)
            if (q2 == tmpos) { tv[q2] = bv; ti[q2] = col; }
          tmin = tv[0]; tmpos = 0;
          #pragma unroll
          for (int q2 = 1; q2 < 8; ++q2)
            if (tv[q2] < tmin) { tmin = tv[q2]; tmpos = q2; }
          #pragma unroll
          for (int j = 0; j < 8; ++j)
            if (j == bj) acc[j] = -INFINITY;
        }
        bv = acc[0]; bj = 0;
        #pragma unroll
        for (int j = 1; j < 8; ++j)
          if (acc[j] > bv) { bv = acc[j]; bj = j; }
      }
    }
    // rare fallback: some lane had >=3 qualifiers in this group
    if (__any(bv > tmin)) {
      #pragma unroll
      for (int j = 0; j < 8; ++j) {
        float v = acc[j];
        if (v > tmin) {
          int col = cb + j;
          #pragma unroll
          for (int q2 = 0; q2 < 8; ++q2)
            if (q2 == tmpos) { tv[q2] = v; ti[q2] = col; }
          tmin = tv[0]; tmpos = 0;
          #pragma unroll
          for (int q2 = 1; q2 < 8; ++q2)
            if (tv[q2] < tmin) { tmin = tv[q2]; tmpos = q2; }
        }
      }
    }
  }

  // 5) block merge: 4 waves x 8 candidates -> chunk-local top-8 per row
  __syncthreads();                 // all q reads done before aliasing cv/ci
  #pragma unroll
  for (int q2 = 0; q2 < 8; ++q2) {
    cv[lane][wu * 8 + q2] = tv[q2];
    ci[lane][wu * 8 + q2] = ti[q2];
  }
  __syncthreads();
  if (t < 64) {
    float rv[8]; int rid[8];
    #pragma unroll
    for (int q2 = 0; q2 < 8; ++q2) { rv[q2] = cv[t][q2]; rid[q2] = ci[t][q2]; }
    float m = rv[0]; int mp = 0;
    #pragma unroll
    for (int q2 = 1; q2 < 8; ++q2) if (rv[q2] < m) { m = rv[q2]; mp = q2; }
    #pragma unroll
    for (int c = 8; c < 32; ++c) {
      float v = cv[t][c];
      if (v > m) {
        int col = ci[t][c];
        #pragma unroll
        for (int q2 = 0; q2 < 8; ++q2) if (q2 == mp) { rv[q2] = v; rid[q2] = col; }
        m = rv[0]; mp = 0;
        #pragma unroll
        for (int q2 = 1; q2 < 8; ++q2) if (rv[q2] < m) { m = rv[q2]; mp = q2; }
      }
    }
    size_t gr = (size_t)rb * 64 + t;
    #pragma unroll
    for (int q2 = 0; q2 < 8; ++q2) {
      wsv[gr * 64 + chunk * 8 + q2] = rv[q2];
      wsi[gr * 64 + chunk * 8 + q2] = rid[q2];
    }
  }
}

// ---------------- Kernel 3: merge 8 chunks, softmax, scatter ----------------
__global__ __launch_bounds__(256) void merge_scatter(
    const float* __restrict__ wsv, const int* __restrict__ wsi,
    float* __restrict__ out) {
  int row = blockIdx.x * 256 + threadIdx.x;  // 0..16383
  const float4* v4 = (const float4*)(wsv + (size_t)row * 64);
  const int4*   i4 = (const int4*)(wsi + (size_t)row * 64);
  float rv[8]; int rid[8];
  {  // seed from first 8 candidates
    float4 a0 = v4[0], a1 = v4[1];
    int4   c0 = i4[0], c1 = i4[1];
    rv[0]=a0.x; rv[1]=a0.y; rv[2]=a0.z; rv[3]=a0.w;
    rv[4]=a1.x; rv[5]=a1.y; rv[6]=a1.z; rv[7]=a1.w;
    rid[0]=c0.x; rid[1]=c0.y; rid[2]=c0.z; rid[3]=c0.w;
    rid[4]=c1.x; rid[5]=c1.y; rid[6]=c1.z; rid[7]=c1.w;
  }
  float m = rv[0]; int mp = 0;
  #pragma unroll
  for (int q = 1; q < 8; ++q) if (rv[q] < m) { m = rv[q]; mp = q; }
  #pragma unroll 2
  for (int c4 = 2; c4 < 16; ++c4) {
    float4 a = v4[c4]; int4 ic = i4[c4];
    const float vv[4] = {a.x, a.y, a.z, a.w};
    const int   ii[4] = {ic.x, ic.y, ic.z, ic.w};
    #pragma unroll
    for (int k = 0; k < 4; ++k) {
      if (vv[k] > m) {
        #pragma unroll
        for (int q = 0; q < 8; ++q) if (q == mp) { rv[q] = vv[k]; rid[q] = ii[k]; }
        m = rv[0]; mp = 0;
        #pragma unroll
        for (int q = 1; q < 8; ++q) if (rv[q] < m) { m = rv[q]; mp = q; }
      }
    }
  }
  float vmax = rv[0];
  #pragma unroll
  for (int q = 1; q < 8; ++q) vmax = fmaxf(vmax, rv[q]);
  float e[8], s = 0.f;
  #pragma unroll
  for (int q = 0; q < 8; ++q) { e[q] = __expf((rv[q] - vmax) * SCALE); s += e[q]; }
  float inv = 1.f / s;
  float* orow = out + (size_t)row * NCOL;
  #pragma unroll
  for (int q = 0; q < 8; ++q) orow[rid[q]] = e[q] * inv;
}

extern "C" void kernel_launch(void* const* d_in, const int* in_sizes, int n_in,
                              void* d_out, int out_size, void* d_ws, size_t ws_size,
                              hipStream_t stream) {
  const float* x  = (const float*)d_in[0];
  const float* Wq = (const float*)d_in[1];
  const float* Wk = (const float*)d_in[2];
  float* out = (float*)d_out;

  char* ws = (char*)d_ws;
  float* Qt  = (float*)ws;                                   // 4 MB
  float* Kt  = (float*)(ws + (size_t)NROW * DKDIM * 4);      // 4 MB
  float* wsv = (float*)(ws + 2 * (size_t)NROW * DKDIM * 4);  // 4 MB
  int*   wsi = (int*)  (ws + 2 * (size_t)NROW * DKDIM * 4 + (size_t)NROW * 64 * 4); // 4 MB

  qk_proj<<<dim3(NROW / 64), 512, 0, stream>>>(x, Wq, Wk, Qt, Kt);
  s_topk<<<2048, 256, 0, stream>>>(Qt, Kt, out, wsv, wsi);
  merge_scatter<<<NROW / 256, 256, 0, stream>>>(wsv, wsi, out);
}